// Round 1
// baseline (973.972 us; speedup 1.0000x reference)
//
#include <hip/hip_runtime.h>
#include <stdint.h>

#define H_ 8
#define D_ 64
#define EMBD 512
#define HD_ 512
#define B_ 4
#define S_ 1024
#define XL_ 1024
#define J_ 2048
#define KK_ 32
#define OUT1 (B_*S_*EMBD)   // 2097152 floats: "out"; kv memory follows

typedef __bf16 bf16x8 __attribute__((ext_vector_type(8)));
typedef float f32x4 __attribute__((ext_vector_type(4)));

__device__ __forceinline__ uint32_t pack2bf(float a, float b) {
    uint32_t ua = __builtin_bit_cast(uint32_t, a);
    uint32_t ub = __builtin_bit_cast(uint32_t, b);
    ua = (ua + 0x7FFFu + ((ua >> 16) & 1u)) >> 16;
    ub = (ub + 0x7FFFu + ((ub >> 16) & 1u)) >> 16;
    return ua | (ub << 16);
}

// ---------------------------------------------------------------------------
// GEMM: out[m,n] = sum_k A[m,k]*W[n,k] + bias[n]   (A:[4096,512], W:[512,512])
// bf16 MFMA 16x16x32. Tile 64x64, BK=64, 256 thr / 4 waves, wave w -> rows w*16..+15.
// mode 0: out[m*512+n]   (q workspace / final out)
// mode 1: out[m*1024+n]          (k -> kv memory [b,s,0,hd])
// mode 2: out[m*1024+512+n]      (v -> kv memory [b,s,1,hd])
// ---------------------------------------------------------------------------
#define GPAD 72

__global__ __launch_bounds__(256) void gemm_bt(
    const float* __restrict__ A, const float* __restrict__ W,
    const float* __restrict__ bias, float* __restrict__ out, int mode)
{
    __shared__ uint16_t a_l[64 * GPAD];
    __shared__ uint16_t w_l[64 * GPAD];
    const int t    = threadIdx.x;
    const int m0   = blockIdx.x * 64;
    const int n0   = blockIdx.y * 64;
    const int wv   = t >> 6;
    const int lane = t & 63;
    const int quad = lane >> 4;
    const int l16  = lane & 15;
    const int lrow = t >> 2;          // staging row 0..63
    const int lseg = (t & 3) * 16;    // staging col (16 floats)

    f32x4 zero = {0.f, 0.f, 0.f, 0.f};
    f32x4 acc[4] = {zero, zero, zero, zero};

    for (int k0 = 0; k0 < EMBD; k0 += 64) {
        const float* ga = A + (size_t)(m0 + lrow) * EMBD + k0 + lseg;
        const float* gw = W + (size_t)(n0 + lrow) * EMBD + k0 + lseg;
        float4 a0 = *(const float4*)(ga);
        float4 a1 = *(const float4*)(ga + 4);
        float4 a2 = *(const float4*)(ga + 8);
        float4 a3 = *(const float4*)(ga + 12);
        float4 w0 = *(const float4*)(gw);
        float4 w1 = *(const float4*)(gw + 4);
        float4 w2 = *(const float4*)(gw + 8);
        float4 w3 = *(const float4*)(gw + 12);
        uint32_t* pa = (uint32_t*)(a_l + lrow * GPAD + lseg);
        uint32_t* pw = (uint32_t*)(w_l + lrow * GPAD + lseg);
        pa[0] = pack2bf(a0.x, a0.y); pa[1] = pack2bf(a0.z, a0.w);
        pa[2] = pack2bf(a1.x, a1.y); pa[3] = pack2bf(a1.z, a1.w);
        pa[4] = pack2bf(a2.x, a2.y); pa[5] = pack2bf(a2.z, a2.w);
        pa[6] = pack2bf(a3.x, a3.y); pa[7] = pack2bf(a3.z, a3.w);
        pw[0] = pack2bf(w0.x, w0.y); pw[1] = pack2bf(w0.z, w0.w);
        pw[2] = pack2bf(w1.x, w1.y); pw[3] = pack2bf(w1.z, w1.w);
        pw[4] = pack2bf(w2.x, w2.y); pw[5] = pack2bf(w2.z, w2.w);
        pw[6] = pack2bf(w3.x, w3.y); pw[7] = pack2bf(w3.z, w3.w);
        __syncthreads();
        #pragma unroll
        for (int ks = 0; ks < 64; ks += 32) {
            bf16x8 af = *(const bf16x8*)(a_l + (wv*16 + l16) * GPAD + ks + quad*8);
            #pragma unroll
            for (int nt = 0; nt < 4; nt++) {
                bf16x8 wf = *(const bf16x8*)(w_l + (nt*16 + l16) * GPAD + ks + quad*8);
                acc[nt] = __builtin_amdgcn_mfma_f32_16x16x32_bf16(af, wf, acc[nt], 0, 0, 0);
            }
        }
        __syncthreads();
    }

    #pragma unroll
    for (int nt = 0; nt < 4; nt++) {
        const int col = n0 + nt*16 + l16;
        const float bvv = bias[col];
        #pragma unroll
        for (int r = 0; r < 4; r++) {
            const int row = m0 + wv*16 + quad*4 + r;
            const float v = acc[nt][r] + bvv;
            if (mode == 0)      out[(size_t)row * EMBD + col] = v;
            else if (mode == 1) out[(size_t)row * 1024 + col] = v;
            else                out[(size_t)row * 1024 + 512 + col] = v;
        }
    }
}

// ---------------------------------------------------------------------------
// Local XL causal attention, flash-style online softmax, bf16 MFMA 16x16x32.
// grid (S/64, H, B), block 256 = 4 waves; wave wv owns rows i0+wv*16 .. +15.
// Per j-tile (64 keys): QK^T via MFMA (Q,K bf16 in LDS, row-major [64][72]),
// online softmax fp32 in-register (lane owns 4 rows x 4 j-subtiles of S, D-layout
// col=l16 row=quad*4+r), P -> per-wave LDS (bf16) -> PV via MFMA with V staged
// d-major [d][j] so both fragment reads are contiguous ds_read_b128.
// score = (q.k + rel_pos[h,i,j]) * scale; allowed j <= i + XL.
// ---------------------------------------------------------------------------
#define APAD 72

__global__ __launch_bounds__(256) void attn_local(
    const float* __restrict__ q_ws,     // [B,S,HD]
    const float* __restrict__ xlm,      // [B,XL,2,HD]
    const float* __restrict__ kv_cur,   // [B,S,2,HD]
    const float* __restrict__ rel,      // [H,S,J]
    float* __restrict__ o_ws)           // [B,S,HD]
{
    __shared__ uint16_t qS[64][APAD];       // bf16 Q rows (row-major)
    __shared__ uint16_t kS[64][APAD];       // bf16 K rows (j-major)
    __shared__ uint16_t vS[64][APAD];       // bf16 V transposed: [d][j]
    __shared__ uint16_t pS[4][16][APAD];    // bf16 P per wave: [i_local][j]

    const int t    = threadIdx.x;
    const int wv   = t >> 6;
    const int lane = t & 63;
    const int quad = lane >> 4;
    const int l16  = lane & 15;
    const int b    = blockIdx.z;
    const int h    = blockIdx.y;
    const int i0   = blockIdx.x * 64;

    {   // stage Q once: thread t -> row t>>2, 16 cols at (t&3)*16
        const int row = t >> 2;
        const int dc  = (t & 3) * 16;
        const float* g = q_ws + (size_t)(b*S_ + i0 + row) * HD_ + h*D_ + dc;
        float4 x0 = *(const float4*)(g);
        float4 x1 = *(const float4*)(g + 4);
        float4 x2 = *(const float4*)(g + 8);
        float4 x3 = *(const float4*)(g + 12);
        uint32_t* d = (uint32_t*)&qS[row][dc];
        d[0] = pack2bf(x0.x, x0.y); d[1] = pack2bf(x0.z, x0.w);
        d[2] = pack2bf(x1.x, x1.y); d[3] = pack2bf(x1.z, x1.w);
        d[4] = pack2bf(x2.x, x2.y); d[5] = pack2bf(x2.z, x2.w);
        d[6] = pack2bf(x3.x, x3.y); d[7] = pack2bf(x3.z, x3.w);
    }

    f32x4 zero = {0.f, 0.f, 0.f, 0.f};
    f32x4 accO[4] = {zero, zero, zero, zero};
    float m_r[4], l_r[4];
    #pragma unroll
    for (int r = 0; r < 4; r++) { m_r[r] = -1e30f; l_r[r] = 0.f; }

    const int irow0  = i0 + wv*16 + quad*4;   // this lane's first query row
    const int ntiles = ((i0 + XL_ + 63) >> 6) + 1;
    const float scale = 0.125f;

    const int kj  = t >> 2;          // K staging: j row 0..63
    const int kdc = (t & 3) * 16;    //            d chunk (16)
    const int vj  = (t & 31) * 2;    // V staging: j pair
    const int vdc = (t >> 5) * 8;    //            d chunk (8)

    for (int tix = 0; tix < ntiles; tix++) {
        const int j0 = tix << 6;
        {   // stage K tile, row-major bf16
            const int jg = j0 + kj;
            const float* g = (jg < XL_)
                ? xlm    + ((size_t)(b*XL_ + jg) * 2    ) * HD_ + h*D_ + kdc
                : kv_cur + ((size_t)(b*S_ + (jg - XL_)) * 2) * HD_ + h*D_ + kdc;
            float4 x0 = *(const float4*)(g);
            float4 x1 = *(const float4*)(g + 4);
            float4 x2 = *(const float4*)(g + 8);
            float4 x3 = *(const float4*)(g + 12);
            uint32_t* d = (uint32_t*)&kS[kj][kdc];
            d[0] = pack2bf(x0.x, x0.y); d[1] = pack2bf(x0.z, x0.w);
            d[2] = pack2bf(x1.x, x1.y); d[3] = pack2bf(x1.z, x1.w);
            d[4] = pack2bf(x2.x, x2.y); d[5] = pack2bf(x2.z, x2.w);
            d[6] = pack2bf(x3.x, x3.y); d[7] = pack2bf(x3.z, x3.w);
        }
        {   // stage V tile transposed: vS[d][j], pack j-pairs into dwords
            const int jg = j0 + vj;
            const float* g0 = (jg < XL_)
                ? xlm    + ((size_t)(b*XL_ + jg) * 2 + 1) * HD_ + h*D_ + vdc
                : kv_cur + ((size_t)(b*S_ + (jg - XL_)) * 2 + 1) * HD_ + h*D_ + vdc;
            const float* g1 = g0 + 2*HD_;   // next j row (tile never straddles XL)
            float4 a0 = *(const float4*)(g0);
            float4 a1 = *(const float4*)(g0 + 4);
            float4 b0 = *(const float4*)(g1);
            float4 b1 = *(const float4*)(g1 + 4);
            *(uint32_t*)&vS[vdc+0][vj] = pack2bf(a0.x, b0.x);
            *(uint32_t*)&vS[vdc+1][vj] = pack2bf(a0.y, b0.y);
            *(uint32_t*)&vS[vdc+2][vj] = pack2bf(a0.z, b0.z);
            *(uint32_t*)&vS[vdc+3][vj] = pack2bf(a0.w, b0.w);
            *(uint32_t*)&vS[vdc+4][vj] = pack2bf(a1.x, b1.x);
            *(uint32_t*)&vS[vdc+5][vj] = pack2bf(a1.y, b1.y);
            *(uint32_t*)&vS[vdc+6][vj] = pack2bf(a1.z, b1.z);
            *(uint32_t*)&vS[vdc+7][vj] = pack2bf(a1.w, b1.w);
        }
        __syncthreads();

        // rel_pos for this lane's 16 S entries (issue early; L3-resident)
        float srel[4][4];
        const float* relbase = rel + ((size_t)h*S_ + irow0) * J_ + j0 + l16;
        #pragma unroll
        for (int r = 0; r < 4; r++)
            #pragma unroll
            for (int jt = 0; jt < 4; jt++)
                srel[r][jt] = relbase[(size_t)r * J_ + jt*16];

        // QK^T: D[row=quad*4+r][col=jt*16+l16]
        bf16x8 aq0 = *(const bf16x8*)&qS[wv*16 + l16][quad*8];
        bf16x8 aq1 = *(const bf16x8*)&qS[wv*16 + l16][32 + quad*8];
        f32x4 sac[4] = {zero, zero, zero, zero};
        #pragma unroll
        for (int jt = 0; jt < 4; jt++) {
            bf16x8 bk0 = *(const bf16x8*)&kS[jt*16 + l16][quad*8];
            bf16x8 bk1 = *(const bf16x8*)&kS[jt*16 + l16][32 + quad*8];
            sac[jt] = __builtin_amdgcn_mfma_f32_16x16x32_bf16(aq0, bk0, sac[jt], 0, 0, 0);
            sac[jt] = __builtin_amdgcn_mfma_f32_16x16x32_bf16(aq1, bk1, sac[jt], 0, 0, 0);
        }

        // causal mask only materializes on the diagonal (last) tile
        const bool need_mask = (j0 + 64 > i0 + XL_);

        float p_[4][4];
        float alpha[4];
        #pragma unroll
        for (int r = 0; r < 4; r++) {
            const int irow = irow0 + r;
            float sv[4];
            #pragma unroll
            for (int jt = 0; jt < 4; jt++) {
                float s = (sac[jt][r] + srel[r][jt]) * scale;
                if (need_mask && (j0 + jt*16 + l16 > irow + XL_)) s = -1e30f;
                sv[jt] = s;
            }
            float mx = fmaxf(fmaxf(sv[0], sv[1]), fmaxf(sv[2], sv[3]));
            #pragma unroll
            for (int off = 8; off >= 1; off >>= 1)
                mx = fmaxf(mx, __shfl_xor(mx, off));
            const float mnew = fmaxf(m_r[r], mx);
            alpha[r] = __expf(m_r[r] - mnew);
            m_r[r] = mnew;
            float ps = 0.f;
            #pragma unroll
            for (int jt = 0; jt < 4; jt++) {
                p_[jt][r] = __expf(sv[jt] - mnew);
                ps += p_[jt][r];
            }
            #pragma unroll
            for (int off = 8; off >= 1; off >>= 1)
                ps += __shfl_xor(ps, off);
            l_r[r] = l_r[r] * alpha[r] + ps;
        }
        #pragma unroll
        for (int dt = 0; dt < 4; dt++)
            #pragma unroll
            for (int r = 0; r < 4; r++)
                accO[dt][r] *= alpha[r];

        // P -> per-wave LDS as bf16 (same-wave RAW; compiler inserts lgkmcnt)
        #pragma unroll
        for (int jt = 0; jt < 4; jt++)
            #pragma unroll
            for (int r = 0; r < 4; r++)
                pS[wv][quad*4 + r][jt*16 + l16] = (uint16_t)pack2bf(p_[jt][r], 0.f);

        // PV: A=P (m=i_local, k=j), B=V^T (n=d, k=j) -> accO[dt][row][col=d]
        #pragma unroll
        for (int kc = 0; kc < 2; kc++) {
            bf16x8 ap = *(const bf16x8*)&pS[wv][l16][kc*32 + quad*8];
            #pragma unroll
            for (int dt = 0; dt < 4; dt++) {
                bf16x8 bv = *(const bf16x8*)&vS[dt*16 + l16][kc*32 + quad*8];
                accO[dt] = __builtin_amdgcn_mfma_f32_16x16x32_bf16(ap, bv, accO[dt], 0, 0, 0);
            }
        }
        __syncthreads();
    }

    #pragma unroll
    for (int r = 0; r < 4; r++) {
        const float inv = 1.f / l_r[r];
        float* o = o_ws + (size_t)(b*S_ + irow0 + r) * HD_ + h*D_ + l16;
        #pragma unroll
        for (int dt = 0; dt < 4; dt++)
            o[dt*16] = accO[dt][r] * inv;
    }
}

// ---------------------------------------------------------------------------
// kNN attention + gate merge. grid 4096 (= b*S+s), block 512: wave = head, lane = d.
// Streams the 512 MB knn tensor exactly once, fully coalesced (2 KB / instr).
// ---------------------------------------------------------------------------
__global__ __launch_bounds__(512) void knn_merge(
    const float* __restrict__ q_ws, const float* __restrict__ knn,
    const float* __restrict__ o_ws, const float* __restrict__ gate,
    float* __restrict__ merged)
{
    __shared__ float p_s[H_][KK_];
    const int t    = threadIdx.x;
    const int wv   = t >> 6;          // head
    const int lane = t & 63;
    const size_t bs = blockIdx.x;
    const float* base = knn + bs * (size_t)(KK_ * 2 * HD_);
    const float qv = q_ws[bs * HD_ + t];

    #pragma unroll 4
    for (int kk = 0; kk < KK_; kk++) {
        float pr = qv * base[(size_t)(kk*2) * HD_ + t];
        #pragma unroll
        for (int off = 32; off >= 1; off >>= 1)
            pr += __shfl_xor(pr, off);
        if (lane == 0) p_s[wv][kk] = pr;
    }
    __syncthreads();

    const float sval = p_s[wv][lane & 31] * 0.125f;
    float mx = sval;
    #pragma unroll
    for (int off = 16; off >= 1; off >>= 1)
        mx = fmaxf(mx, __shfl_xor(mx, off));
    const float e = __expf(sval - mx);
    float es = e;
    #pragma unroll
    for (int off = 16; off >= 1; off >>= 1)
        es += __shfl_xor(es, off);
    if (lane < 32) p_s[wv][lane] = e / es;
    __syncthreads();

    float acc = 0.f;
    #pragma unroll 4
    for (int kk = 0; kk < KK_; kk++)
        acc += p_s[wv][kk] * base[(size_t)(kk*2 + 1) * HD_ + t];

    const float g = 1.f / (1.f + __expf(-gate[wv]));
    const float o = o_ws[bs * HD_ + t];
    merged[bs * HD_ + t] = o * g + acc * (1.f - g);
}

// ---------------------------------------------------------------------------
extern "C" void kernel_launch(void* const* d_in, const int* in_sizes, int n_in,
                              void* d_out, int out_size, void* d_ws, size_t ws_size,
                              hipStream_t stream)
{
    (void)in_sizes; (void)n_in; (void)out_size; (void)ws_size;
    const float* x    = (const float*)d_in[0];
    const float* rel  = (const float*)d_in[1];
    const float* xlm  = (const float*)d_in[2];
    const float* knn  = (const float*)d_in[3];
    const float* Wq   = (const float*)d_in[4];
    const float* bq   = (const float*)d_in[5];
    const float* Wk   = (const float*)d_in[6];
    const float* bk   = (const float*)d_in[7];
    const float* Wv   = (const float*)d_in[8];
    const float* bv   = (const float*)d_in[9];
    const float* Wo   = (const float*)d_in[10];
    const float* bo   = (const float*)d_in[11];
    const float* gate = (const float*)d_in[12];

    float* out    = (float*)d_out;
    float* kv_out = out + OUT1;           // [B,S,2,HD] second output
    float* q_ws   = (float*)d_ws;         // [B,S,HD]
    float* o_ws   = q_ws + OUT1;          // [B,S,HD] local-attn out
    float* mg_ws  = o_ws + OUT1;          // [B,S,HD] merged

    dim3 gg(64, 8, 1);
    gemm_bt<<<gg, 256, 0, stream>>>(x, Wq, bq, q_ws, 0);
    gemm_bt<<<gg, 256, 0, stream>>>(x, Wk, bk, kv_out, 1);
    gemm_bt<<<gg, 256, 0, stream>>>(x, Wv, bv, kv_out, 2);
    attn_local<<<dim3(16, 8, 4), 256, 0, stream>>>(q_ws, xlm, kv_out, rel, o_ws);
    knn_merge<<<dim3(4096), 512, 0, stream>>>(q_ws, knn, o_ws, gate, mg_ws);
    gemm_bt<<<gg, 256, 0, stream>>>(mg_ws, Wo, bo, out, 0);
}

// Round 3
// 934.563 us; speedup vs baseline: 1.0422x; 1.0422x over previous
//
#include <hip/hip_runtime.h>
#include <stdint.h>

#define H_ 8
#define D_ 64
#define EMBD 512
#define HD_ 512
#define B_ 4
#define S_ 1024
#define XL_ 1024
#define J_ 2048
#define KK_ 32
#define OUT1 (B_*S_*EMBD)   // 2097152 floats: "out"; kv memory follows

typedef __bf16 bf16x8 __attribute__((ext_vector_type(8)));
typedef float f32x4 __attribute__((ext_vector_type(4)));

__device__ __forceinline__ uint32_t pack2bf(float a, float b) {
    uint32_t ua = __builtin_bit_cast(uint32_t, a);
    uint32_t ub = __builtin_bit_cast(uint32_t, b);
    ua = (ua + 0x7FFFu + ((ua >> 16) & 1u)) >> 16;
    ub = (ub + 0x7FFFu + ((ub >> 16) & 1u)) >> 16;
    return ua | (ub << 16);
}

// ---------------------------------------------------------------------------
// GEMM tile body: out[m,n] = sum_k A[m,k]*W[n,k] + bias[n]  (A:[4096,512], W:[512,512])
// bf16 MFMA 16x16x32. Tile 64x64, BK=64, 256 thr / 4 waves, wave w -> rows w*16..+15.
// Register-prefetch pipeline: next K-tile's global loads issue right after the
// LDS-ready barrier and retire during the MFMA phase (T14 async-STAGE).
// mode 0: out[m*512+n]   (q workspace / final out)
// mode 1: out[m*1024+n]          (k -> kv memory [b,s,0,hd])
// mode 2: out[m*1024+512+n]      (v -> kv memory [b,s,1,hd])
// ---------------------------------------------------------------------------
#define GPAD 72

__device__ __forceinline__ void gemm_tile_body(
    const float* __restrict__ A, const float* __restrict__ W,
    const float* __restrict__ bias, float* __restrict__ out, int mode,
    uint16_t* a_l, uint16_t* w_l, int m0, int n0)
{
    const int t    = threadIdx.x;
    const int wv   = t >> 6;
    const int lane = t & 63;
    const int quad = lane >> 4;
    const int l16  = lane & 15;
    const int lrow = t >> 2;          // staging row 0..63
    const int lseg = (t & 3) * 16;    // staging col (16 floats)

    const float* gab = A + (size_t)(m0 + lrow) * EMBD + lseg;
    const float* gwb = W + (size_t)(n0 + lrow) * EMBD + lseg;

    f32x4 zero = {0.f, 0.f, 0.f, 0.f};
    f32x4 acc[4] = {zero, zero, zero, zero};

    // preload K-tile 0 into registers
    float4 a0 = *(const float4*)(gab);
    float4 a1 = *(const float4*)(gab + 4);
    float4 a2 = *(const float4*)(gab + 8);
    float4 a3 = *(const float4*)(gab + 12);
    float4 w0 = *(const float4*)(gwb);
    float4 w1 = *(const float4*)(gwb + 4);
    float4 w2 = *(const float4*)(gwb + 8);
    float4 w3 = *(const float4*)(gwb + 12);

    for (int k0 = 0; k0 < EMBD; k0 += 64) {
        uint32_t* pa = (uint32_t*)(a_l + lrow * GPAD + lseg);
        uint32_t* pw = (uint32_t*)(w_l + lrow * GPAD + lseg);
        pa[0] = pack2bf(a0.x, a0.y); pa[1] = pack2bf(a0.z, a0.w);
        pa[2] = pack2bf(a1.x, a1.y); pa[3] = pack2bf(a1.z, a1.w);
        pa[4] = pack2bf(a2.x, a2.y); pa[5] = pack2bf(a2.z, a2.w);
        pa[6] = pack2bf(a3.x, a3.y); pa[7] = pack2bf(a3.z, a3.w);
        pw[0] = pack2bf(w0.x, w0.y); pw[1] = pack2bf(w0.z, w0.w);
        pw[2] = pack2bf(w1.x, w1.y); pw[3] = pack2bf(w1.z, w1.w);
        pw[4] = pack2bf(w2.x, w2.y); pw[5] = pack2bf(w2.z, w2.w);
        pw[6] = pack2bf(w3.x, w3.y); pw[7] = pack2bf(w3.z, w3.w);
        __syncthreads();

        if (k0 + 64 < EMBD) {   // prefetch next K-tile; retires under MFMA
            const float* ga = gab + k0 + 64;
            const float* gw = gwb + k0 + 64;
            a0 = *(const float4*)(ga);
            a1 = *(const float4*)(ga + 4);
            a2 = *(const float4*)(ga + 8);
            a3 = *(const float4*)(ga + 12);
            w0 = *(const float4*)(gw);
            w1 = *(const float4*)(gw + 4);
            w2 = *(const float4*)(gw + 8);
            w3 = *(const float4*)(gw + 12);
        }

        #pragma unroll
        for (int ks = 0; ks < 64; ks += 32) {
            bf16x8 af = *(const bf16x8*)(a_l + (wv*16 + l16) * GPAD + ks + quad*8);
            #pragma unroll
            for (int nt = 0; nt < 4; nt++) {
                bf16x8 wf = *(const bf16x8*)(w_l + (nt*16 + l16) * GPAD + ks + quad*8);
                acc[nt] = __builtin_amdgcn_mfma_f32_16x16x32_bf16(af, wf, acc[nt], 0, 0, 0);
            }
        }
        __syncthreads();
    }

    #pragma unroll
    for (int nt = 0; nt < 4; nt++) {
        const int col = n0 + nt*16 + l16;
        const float bvv = bias[col];
        #pragma unroll
        for (int r = 0; r < 4; r++) {
            const int row = m0 + wv*16 + quad*4 + r;
            const float v = acc[nt][r] + bvv;
            if (mode == 0)      out[(size_t)row * EMBD + col] = v;
            else if (mode == 1) out[(size_t)row * 1024 + col] = v;
            else                out[(size_t)row * 1024 + 512 + col] = v;
        }
    }
}

__global__ __launch_bounds__(256) void gemm_bt(
    const float* __restrict__ A, const float* __restrict__ W,
    const float* __restrict__ bias, float* __restrict__ out, int mode)
{
    __shared__ uint16_t a_l[64 * GPAD];
    __shared__ uint16_t w_l[64 * GPAD];
    gemm_tile_body(A, W, bias, out, mode, a_l, w_l, blockIdx.x * 64, blockIdx.y * 64);
}

// Fused QKV: grid.z = 0/1/2 selects weight/bias/destination. One launch fills
// the machine (1536 blocks vs 3x512) and removes two inter-launch bubbles.
__global__ __launch_bounds__(256) void gemm_qkv(
    const float* __restrict__ A,
    const float* __restrict__ Wq, const float* __restrict__ bq,
    const float* __restrict__ Wk, const float* __restrict__ bk,
    const float* __restrict__ Wv, const float* __restrict__ bv,
    float* __restrict__ q_ws, float* __restrict__ kv_out)
{
    __shared__ uint16_t a_l[64 * GPAD];
    __shared__ uint16_t w_l[64 * GPAD];
    const int mode = blockIdx.z;
    const float* W    = (mode == 0) ? Wq : (mode == 1) ? Wk : Wv;
    const float* bias = (mode == 0) ? bq : (mode == 1) ? bk : bv;
    float* out        = (mode == 0) ? q_ws : kv_out;
    gemm_tile_body(A, W, bias, out, mode, a_l, w_l, blockIdx.x * 64, blockIdx.y * 64);
}

// ---------------------------------------------------------------------------
// Local XL causal attention, flash-style online softmax, bf16 MFMA 16x16x32.
// grid (S/64, H, B), block 256 = 4 waves; wave wv owns rows i0+wv*16 .. +15.
// Register-prefetch pipeline on the K/V staging (grid is only 2 blocks/CU so
// stage latency is otherwise fully exposed). Q fragments hoisted out of the
// tile loop (loop-invariant).
// score = (q.k + rel_pos[h,i,j]) * scale; allowed j <= i + XL.
// ---------------------------------------------------------------------------
#define APAD 72

__global__ __launch_bounds__(256) void attn_local(
    const float* __restrict__ q_ws,     // [B,S,HD]
    const float* __restrict__ xlm,      // [B,XL,2,HD]
    const float* __restrict__ kv_cur,   // [B,S,2,HD]
    const float* __restrict__ rel,      // [H,S,J]
    float* __restrict__ o_ws)           // [B,S,HD]
{
    __shared__ uint16_t qS[64][APAD];       // bf16 Q rows (row-major)
    __shared__ uint16_t kS[64][APAD];       // bf16 K rows (j-major)
    __shared__ uint16_t vS[64][APAD];       // bf16 V transposed: [d][j]
    __shared__ uint16_t pS[4][16][APAD];    // bf16 P per wave: [i_local][j]

    const int t    = threadIdx.x;
    const int wv   = t >> 6;
    const int lane = t & 63;
    const int quad = lane >> 4;
    const int l16  = lane & 15;
    const int b    = blockIdx.z;
    const int h    = blockIdx.y;
    const int i0   = blockIdx.x * 64;

    const int irow0  = i0 + wv*16 + quad*4;   // this lane's first query row
    const int ntiles = ((i0 + XL_ + 63) >> 6) + 1;
    const float scale = 0.125f;

    const int kj  = t >> 2;          // K staging: j row 0..63
    const int kdc = (t & 3) * 16;    //            d chunk (16)
    const int vj  = (t & 31) * 2;    // V staging: j pair
    const int vdc = (t >> 5) * 8;    //            d chunk (8)

    {   // stage Q once: thread t -> row t>>2, 16 cols at (t&3)*16
        const int row = t >> 2;
        const int dc  = (t & 3) * 16;
        const float* g = q_ws + (size_t)(b*S_ + i0 + row) * HD_ + h*D_ + dc;
        float4 x0 = *(const float4*)(g);
        float4 x1 = *(const float4*)(g + 4);
        float4 x2 = *(const float4*)(g + 8);
        float4 x3 = *(const float4*)(g + 12);
        uint32_t* d = (uint32_t*)&qS[row][dc];
        d[0] = pack2bf(x0.x, x0.y); d[1] = pack2bf(x0.z, x0.w);
        d[2] = pack2bf(x1.x, x1.y); d[3] = pack2bf(x1.z, x1.w);
        d[4] = pack2bf(x2.x, x2.y); d[5] = pack2bf(x2.z, x2.w);
        d[6] = pack2bf(x3.x, x3.y); d[7] = pack2bf(x3.z, x3.w);
    }

    // preload K/V tile 0 into registers
    float4 kx0, kx1, kx2, kx3, va0, va1, vb0, vb1;
    {
        const int jg = kj;   // j0 = 0
        const float* g = (jg < XL_)
            ? xlm + ((size_t)(b*XL_ + jg) * 2) * HD_ + h*D_ + kdc
            : kv_cur + ((size_t)(b*S_ + (jg - XL_)) * 2) * HD_ + h*D_ + kdc;
        kx0 = *(const float4*)(g);
        kx1 = *(const float4*)(g + 4);
        kx2 = *(const float4*)(g + 8);
        kx3 = *(const float4*)(g + 12);
        const int jgv = vj;
        const float* g0 = (jgv < XL_)
            ? xlm + ((size_t)(b*XL_ + jgv) * 2 + 1) * HD_ + h*D_ + vdc
            : kv_cur + ((size_t)(b*S_ + (jgv - XL_)) * 2 + 1) * HD_ + h*D_ + vdc;
        va0 = *(const float4*)(g0);
        va1 = *(const float4*)(g0 + 4);
        vb0 = *(const float4*)(g0 + 2*HD_);
        vb1 = *(const float4*)(g0 + 2*HD_ + 4);
    }

    __syncthreads();    // Q visible to all waves
    const bf16x8 aq0 = *(const bf16x8*)&qS[wv*16 + l16][quad*8];
    const bf16x8 aq1 = *(const bf16x8*)&qS[wv*16 + l16][32 + quad*8];

    f32x4 zero = {0.f, 0.f, 0.f, 0.f};
    f32x4 accO[4] = {zero, zero, zero, zero};
    float m_r[4], l_r[4];
    #pragma unroll
    for (int r = 0; r < 4; r++) { m_r[r] = -1e30f; l_r[r] = 0.f; }

    const float* relbase = rel + ((size_t)h*S_ + irow0) * J_ + l16;

    for (int tix = 0; tix < ntiles; tix++) {
        const int j0 = tix << 6;
        {   // pack prefetched K tile -> LDS (row-major bf16)
            uint32_t* d = (uint32_t*)&kS[kj][kdc];
            d[0] = pack2bf(kx0.x, kx0.y); d[1] = pack2bf(kx0.z, kx0.w);
            d[2] = pack2bf(kx1.x, kx1.y); d[3] = pack2bf(kx1.z, kx1.w);
            d[4] = pack2bf(kx2.x, kx2.y); d[5] = pack2bf(kx2.z, kx2.w);
            d[6] = pack2bf(kx3.x, kx3.y); d[7] = pack2bf(kx3.z, kx3.w);
        }
        {   // pack prefetched V tile -> LDS transposed: vS[d][j]
            *(uint32_t*)&vS[vdc+0][vj] = pack2bf(va0.x, vb0.x);
            *(uint32_t*)&vS[vdc+1][vj] = pack2bf(va0.y, vb0.y);
            *(uint32_t*)&vS[vdc+2][vj] = pack2bf(va0.z, vb0.z);
            *(uint32_t*)&vS[vdc+3][vj] = pack2bf(va0.w, vb0.w);
            *(uint32_t*)&vS[vdc+4][vj] = pack2bf(va1.x, vb1.x);
            *(uint32_t*)&vS[vdc+5][vj] = pack2bf(va1.y, vb1.y);
            *(uint32_t*)&vS[vdc+6][vj] = pack2bf(va1.z, vb1.z);
            *(uint32_t*)&vS[vdc+7][vj] = pack2bf(va1.w, vb1.w);
        }
        __syncthreads();

        if (tix + 1 < ntiles) {   // prefetch next K/V tile; retires under MFMA/softmax
            const int jg = j0 + 64 + kj;
            const float* g = (jg < XL_)
                ? xlm + ((size_t)(b*XL_ + jg) * 2) * HD_ + h*D_ + kdc
                : kv_cur + ((size_t)(b*S_ + (jg - XL_)) * 2) * HD_ + h*D_ + kdc;
            kx0 = *(const float4*)(g);
            kx1 = *(const float4*)(g + 4);
            kx2 = *(const float4*)(g + 8);
            kx3 = *(const float4*)(g + 12);
            const int jgv = j0 + 64 + vj;
            const float* g0 = (jgv < XL_)
                ? xlm + ((size_t)(b*XL_ + jgv) * 2 + 1) * HD_ + h*D_ + vdc
                : kv_cur + ((size_t)(b*S_ + (jgv - XL_)) * 2 + 1) * HD_ + h*D_ + vdc;
            va0 = *(const float4*)(g0);
            va1 = *(const float4*)(g0 + 4);
            vb0 = *(const float4*)(g0 + 2*HD_);
            vb1 = *(const float4*)(g0 + 2*HD_ + 4);
        }

        // rel_pos for this lane's 16 S entries (issue early; L3-resident)
        float srel[4][4];
        const float* rb = relbase + j0;
        #pragma unroll
        for (int r = 0; r < 4; r++)
            #pragma unroll
            for (int jt = 0; jt < 4; jt++)
                srel[r][jt] = rb[(size_t)r * J_ + jt*16];

        // QK^T: D[row=quad*4+r][col=jt*16+l16]
        f32x4 sac[4] = {zero, zero, zero, zero};
        #pragma unroll
        for (int jt = 0; jt < 4; jt++) {
            bf16x8 bk0 = *(const bf16x8*)&kS[jt*16 + l16][quad*8];
            bf16x8 bk1 = *(const bf16x8*)&kS[jt*16 + l16][32 + quad*8];
            sac[jt] = __builtin_amdgcn_mfma_f32_16x16x32_bf16(aq0, bk0, sac[jt], 0, 0, 0);
            sac[jt] = __builtin_amdgcn_mfma_f32_16x16x32_bf16(aq1, bk1, sac[jt], 0, 0, 0);
        }

        // causal mask only materializes on the diagonal (last) tile
        const bool need_mask = (j0 + 64 > i0 + XL_);

        float p_[4][4];
        float alpha[4];
        #pragma unroll
        for (int r = 0; r < 4; r++) {
            const int irow = irow0 + r;
            float sv[4];
            #pragma unroll
            for (int jt = 0; jt < 4; jt++) {
                float s = (sac[jt][r] + srel[r][jt]) * scale;
                if (need_mask && (j0 + jt*16 + l16 > irow + XL_)) s = -1e30f;
                sv[jt] = s;
            }
            float mx = fmaxf(fmaxf(sv[0], sv[1]), fmaxf(sv[2], sv[3]));
            #pragma unroll
            for (int off = 8; off >= 1; off >>= 1)
                mx = fmaxf(mx, __shfl_xor(mx, off));
            const float mnew = fmaxf(m_r[r], mx);
            alpha[r] = __expf(m_r[r] - mnew);
            m_r[r] = mnew;
            float ps = 0.f;
            #pragma unroll
            for (int jt = 0; jt < 4; jt++) {
                p_[jt][r] = __expf(sv[jt] - mnew);
                ps += p_[jt][r];
            }
            #pragma unroll
            for (int off = 8; off >= 1; off >>= 1)
                ps += __shfl_xor(ps, off);
            l_r[r] = l_r[r] * alpha[r] + ps;
        }
        #pragma unroll
        for (int dt = 0; dt < 4; dt++)
            #pragma unroll
            for (int r = 0; r < 4; r++)
                accO[dt][r] *= alpha[r];

        // P -> per-wave LDS as bf16 (same-wave RAW; compiler inserts lgkmcnt)
        #pragma unroll
        for (int jt = 0; jt < 4; jt++)
            #pragma unroll
            for (int r = 0; r < 4; r++)
                pS[wv][quad*4 + r][jt*16 + l16] = (uint16_t)pack2bf(p_[jt][r], 0.f);

        // PV: A=P (m=i_local, k=j), B=V^T (n=d, k=j) -> accO[dt][row][col=d]
        #pragma unroll
        for (int kc = 0; kc < 2; kc++) {
            bf16x8 ap = *(const bf16x8*)&pS[wv][l16][kc*32 + quad*8];
            #pragma unroll
            for (int dt = 0; dt < 4; dt++) {
                bf16x8 bv = *(const bf16x8*)&vS[dt*16 + l16][kc*32 + quad*8];
                accO[dt] = __builtin_amdgcn_mfma_f32_16x16x32_bf16(ap, bv, accO[dt], 0, 0, 0);
            }
        }
        __syncthreads();
    }

    #pragma unroll
    for (int r = 0; r < 4; r++) {
        const float inv = 1.f / l_r[r];
        float* o = o_ws + (size_t)(b*S_ + irow0 + r) * HD_ + h*D_ + l16;
        #pragma unroll
        for (int dt = 0; dt < 4; dt++)
            o[dt*16] = accO[dt][r] * inv;
    }
}

// ---------------------------------------------------------------------------
// kNN attention + gate merge. grid 4096 (= b*S+s), block 512: wave = head, lane = d.
// Streams the 512 MB knn tensor exactly once, fully coalesced (2 KB / instr).
// ---------------------------------------------------------------------------
__global__ __launch_bounds__(512) void knn_merge(
    const float* __restrict__ q_ws, const float* __restrict__ knn,
    const float* __restrict__ o_ws, const float* __restrict__ gate,
    float* __restrict__ merged)
{
    __shared__ float p_s[H_][KK_];
    const int t    = threadIdx.x;
    const int wv   = t >> 6;          // head
    const int lane = t & 63;
    const size_t bs = blockIdx.x;
    const float* base = knn + bs * (size_t)(KK_ * 2 * HD_);
    const float qv = q_ws[bs * HD_ + t];

    #pragma unroll 4
    for (int kk = 0; kk < KK_; kk++) {
        float pr = qv * base[(size_t)(kk*2) * HD_ + t];
        #pragma unroll
        for (int off = 32; off >= 1; off >>= 1)
            pr += __shfl_xor(pr, off);
        if (lane == 0) p_s[wv][kk] = pr;
    }
    __syncthreads();

    const float sval = p_s[wv][lane & 31] * 0.125f;
    float mx = sval;
    #pragma unroll
    for (int off = 16; off >= 1; off >>= 1)
        mx = fmaxf(mx, __shfl_xor(mx, off));
    const float e = __expf(sval - mx);
    float es = e;
    #pragma unroll
    for (int off = 16; off >= 1; off >>= 1)
        es += __shfl_xor(es, off);
    if (lane < 32) p_s[wv][lane] = e / es;
    __syncthreads();

    float acc = 0.f;
    #pragma unroll 4
    for (int kk = 0; kk < KK_; kk++)
        acc += p_s[wv][kk] * base[(size_t)(kk*2 + 1) * HD_ + t];

    const float g = 1.f / (1.f + __expf(-gate[wv]));
    const float o = o_ws[bs * HD_ + t];
    merged[bs * HD_ + t] = o * g + acc * (1.f - g);
}

// ---------------------------------------------------------------------------
extern "C" void kernel_launch(void* const* d_in, const int* in_sizes, int n_in,
                              void* d_out, int out_size, void* d_ws, size_t ws_size,
                              hipStream_t stream)
{
    (void)in_sizes; (void)n_in; (void)out_size; (void)ws_size;
    const float* x    = (const float*)d_in[0];
    const float* rel  = (const float*)d_in[1];
    const float* xlm  = (const float*)d_in[2];
    const float* knn  = (const float*)d_in[3];
    const float* Wq   = (const float*)d_in[4];
    const float* bq   = (const float*)d_in[5];
    const float* Wk   = (const float*)d_in[6];
    const float* bk   = (const float*)d_in[7];
    const float* Wv   = (const float*)d_in[8];
    const float* bv   = (const float*)d_in[9];
    const float* Wo   = (const float*)d_in[10];
    const float* bo   = (const float*)d_in[11];
    const float* gate = (const float*)d_in[12];

    float* out    = (float*)d_out;
    float* kv_out = out + OUT1;           // [B,S,2,HD] second output
    float* q_ws   = (float*)d_ws;         // [B,S,HD]
    float* o_ws   = q_ws + OUT1;          // [B,S,HD] local-attn out
    float* mg_ws  = o_ws + OUT1;          // [B,S,HD] merged

    gemm_qkv<<<dim3(64, 8, 3), 256, 0, stream>>>(x, Wq, bq, Wk, bk, Wv, bv, q_ws, kv_out);
    attn_local<<<dim3(16, 8, 4), 256, 0, stream>>>(q_ws, xlm, kv_out, rel, o_ws);
    knn_merge<<<dim3(4096), 512, 0, stream>>>(q_ws, knn, o_ws, gate, mg_ws);
    gemm_bt<<<dim3(64, 8, 1), 256, 0, stream>>>(mg_ws, Wo, bo, out, 0);
}

// Round 5
// 913.362 us; speedup vs baseline: 1.0664x; 1.0232x over previous
//
#include <hip/hip_runtime.h>
#include <stdint.h>

#define H_ 8
#define D_ 64
#define EMBD 512
#define HD_ 512
#define B_ 4
#define S_ 1024
#define XL_ 1024
#define J_ 2048
#define KK_ 32
#define OUT1 (B_*S_*EMBD)   // 2097152 floats: "out"; kv memory follows

typedef __bf16 bf16x8 __attribute__((ext_vector_type(8)));
typedef float f32x4 __attribute__((ext_vector_type(4)));

__device__ __forceinline__ uint32_t pack2bf(float a, float b) {
    uint32_t ua = __builtin_bit_cast(uint32_t, a);
    uint32_t ub = __builtin_bit_cast(uint32_t, b);
    ua = (ua + 0x7FFFu + ((ua >> 16) & 1u)) >> 16;
    ub = (ub + 0x7FFFu + ((ub >> 16) & 1u)) >> 16;
    return ua | (ub << 16);
}

// ---------------------------------------------------------------------------
// GEMM tile body: out[m,n] = sum_k A[m,k]*W[n,k] + bias[n]  (A:[4096,512], W:[512,512])
// bf16 MFMA 16x16x32. Tile 64x64, BK=64, 256 thr / 4 waves, wave w -> rows w*16..+15.
// Register-prefetch pipeline (T14): next K-tile's loads issue after the barrier
// and retire under the MFMA phase.
// mode 0: out[m*512+n]; mode 1: out[m*1024+n] (k); mode 2: out[m*1024+512+n] (v)
// ---------------------------------------------------------------------------
#define GPAD 72

__device__ __forceinline__ void gemm_tile_body(
    const float* __restrict__ A, const float* __restrict__ W,
    const float* __restrict__ bias, float* __restrict__ out, int mode,
    uint16_t* a_l, uint16_t* w_l, int m0, int n0)
{
    const int t    = threadIdx.x;
    const int wv   = t >> 6;
    const int lane = t & 63;
    const int quad = lane >> 4;
    const int l16  = lane & 15;
    const int lrow = t >> 2;          // staging row 0..63
    const int lseg = (t & 3) * 16;    // staging col (16 floats)

    const float* gab = A + (size_t)(m0 + lrow) * EMBD + lseg;
    const float* gwb = W + (size_t)(n0 + lrow) * EMBD + lseg;

    f32x4 zero = {0.f, 0.f, 0.f, 0.f};
    f32x4 acc[4] = {zero, zero, zero, zero};

    float4 a0 = *(const float4*)(gab);
    float4 a1 = *(const float4*)(gab + 4);
    float4 a2 = *(const float4*)(gab + 8);
    float4 a3 = *(const float4*)(gab + 12);
    float4 w0 = *(const float4*)(gwb);
    float4 w1 = *(const float4*)(gwb + 4);
    float4 w2 = *(const float4*)(gwb + 8);
    float4 w3 = *(const float4*)(gwb + 12);

    for (int k0 = 0; k0 < EMBD; k0 += 64) {
        uint32_t* pa = (uint32_t*)(a_l + lrow * GPAD + lseg);
        uint32_t* pw = (uint32_t*)(w_l + lrow * GPAD + lseg);
        pa[0] = pack2bf(a0.x, a0.y); pa[1] = pack2bf(a0.z, a0.w);
        pa[2] = pack2bf(a1.x, a1.y); pa[3] = pack2bf(a1.z, a1.w);
        pa[4] = pack2bf(a2.x, a2.y); pa[5] = pack2bf(a2.z, a2.w);
        pa[6] = pack2bf(a3.x, a3.y); pa[7] = pack2bf(a3.z, a3.w);
        pw[0] = pack2bf(w0.x, w0.y); pw[1] = pack2bf(w0.z, w0.w);
        pw[2] = pack2bf(w1.x, w1.y); pw[3] = pack2bf(w1.z, w1.w);
        pw[4] = pack2bf(w2.x, w2.y); pw[5] = pack2bf(w2.z, w2.w);
        pw[6] = pack2bf(w3.x, w3.y); pw[7] = pack2bf(w3.z, w3.w);
        __syncthreads();

        if (k0 + 64 < EMBD) {
            const float* ga = gab + k0 + 64;
            const float* gw = gwb + k0 + 64;
            a0 = *(const float4*)(ga);
            a1 = *(const float4*)(ga + 4);
            a2 = *(const float4*)(ga + 8);
            a3 = *(const float4*)(ga + 12);
            w0 = *(const float4*)(gw);
            w1 = *(const float4*)(gw + 4);
            w2 = *(const float4*)(gw + 8);
            w3 = *(const float4*)(gw + 12);
        }

        #pragma unroll
        for (int ks = 0; ks < 64; ks += 32) {
            bf16x8 af = *(const bf16x8*)(a_l + (wv*16 + l16) * GPAD + ks + quad*8);
            #pragma unroll
            for (int nt = 0; nt < 4; nt++) {
                bf16x8 wf = *(const bf16x8*)(w_l + (nt*16 + l16) * GPAD + ks + quad*8);
                acc[nt] = __builtin_amdgcn_mfma_f32_16x16x32_bf16(af, wf, acc[nt], 0, 0, 0);
            }
        }
        __syncthreads();
    }

    #pragma unroll
    for (int nt = 0; nt < 4; nt++) {
        const int col = n0 + nt*16 + l16;
        const float bvv = bias[col];
        #pragma unroll
        for (int r = 0; r < 4; r++) {
            const int row = m0 + wv*16 + quad*4 + r;
            const float v = acc[nt][r] + bvv;
            if (mode == 0)      out[(size_t)row * EMBD + col] = v;
            else if (mode == 1) out[(size_t)row * 1024 + col] = v;
            else                out[(size_t)row * 1024 + 512 + col] = v;
        }
    }
}

// Fused QKV: grid.z = 0/1/2 selects weight/bias/destination.
__global__ __launch_bounds__(256) void gemm_qkv(
    const float* __restrict__ A,
    const float* __restrict__ Wq, const float* __restrict__ bq,
    const float* __restrict__ Wk, const float* __restrict__ bk,
    const float* __restrict__ Wv, const float* __restrict__ bv,
    float* __restrict__ q_ws, float* __restrict__ kv_out)
{
    __shared__ uint16_t a_l[64 * GPAD];
    __shared__ uint16_t w_l[64 * GPAD];
    const int mode = blockIdx.z;
    const float* W    = (mode == 0) ? Wq : (mode == 1) ? Wk : Wv;
    const float* bias = (mode == 0) ? bq : (mode == 1) ? bk : bv;
    float* out        = (mode == 0) ? q_ws : kv_out;
    gemm_tile_body(A, W, bias, out, mode, a_l, w_l, blockIdx.x * 64, blockIdx.y * 64);
}

// ---------------------------------------------------------------------------
// Output GEMM with fused gate-merge in A-staging:
//   A[m,k] = ext[m,k] + (o[m,k]-ext[m,k])*sigmoid(gate[k>>6])   (head = k>>6,
//   wave-uniform per K-chunk since BK=64 == D). Then out = A @ Wo^T + bo.
// ---------------------------------------------------------------------------
__global__ __launch_bounds__(256) void gemm_out(
    const float* __restrict__ o_ws, const float* __restrict__ ext_ws,
    const float* __restrict__ gate, const float* __restrict__ W,
    const float* __restrict__ bias, float* __restrict__ out)
{
    __shared__ uint16_t a_l[64 * GPAD];
    __shared__ uint16_t w_l[64 * GPAD];
    const int t    = threadIdx.x;
    const int m0   = blockIdx.x * 64;
    const int n0   = blockIdx.y * 64;
    const int wv   = t >> 6;
    const int lane = t & 63;
    const int quad = lane >> 4;
    const int l16  = lane & 15;
    const int lrow = t >> 2;
    const int lseg = (t & 3) * 16;

    const size_t arow = (size_t)(m0 + lrow) * HD_ + lseg;
    const float* gob = o_ws + arow;
    const float* geb = ext_ws + arow;
    const float* gwb = W + (size_t)(n0 + lrow) * EMBD + lseg;

    f32x4 zero = {0.f, 0.f, 0.f, 0.f};
    f32x4 acc[4] = {zero, zero, zero, zero};

    float4 o0 = *(const float4*)(gob);
    float4 o1 = *(const float4*)(gob + 4);
    float4 o2 = *(const float4*)(gob + 8);
    float4 o3 = *(const float4*)(gob + 12);
    float4 e0 = *(const float4*)(geb);
    float4 e1 = *(const float4*)(geb + 4);
    float4 e2 = *(const float4*)(geb + 8);
    float4 e3 = *(const float4*)(geb + 12);
    float4 w0 = *(const float4*)(gwb);
    float4 w1 = *(const float4*)(gwb + 4);
    float4 w2 = *(const float4*)(gwb + 8);
    float4 w3 = *(const float4*)(gwb + 12);

    for (int k0 = 0; k0 < EMBD; k0 += 64) {
        const float gh = 1.f / (1.f + __expf(-gate[k0 >> 6]));   // head = k0/64, block-uniform
        uint32_t* pa = (uint32_t*)(a_l + lrow * GPAD + lseg);
        uint32_t* pw = (uint32_t*)(w_l + lrow * GPAD + lseg);
        pa[0] = pack2bf(e0.x + (o0.x - e0.x)*gh, e0.y + (o0.y - e0.y)*gh);
        pa[1] = pack2bf(e0.z + (o0.z - e0.z)*gh, e0.w + (o0.w - e0.w)*gh);
        pa[2] = pack2bf(e1.x + (o1.x - e1.x)*gh, e1.y + (o1.y - e1.y)*gh);
        pa[3] = pack2bf(e1.z + (o1.z - e1.z)*gh, e1.w + (o1.w - e1.w)*gh);
        pa[4] = pack2bf(e2.x + (o2.x - e2.x)*gh, e2.y + (o2.y - e2.y)*gh);
        pa[5] = pack2bf(e2.z + (o2.z - e2.z)*gh, e2.w + (o2.w - e2.w)*gh);
        pa[6] = pack2bf(e3.x + (o3.x - e3.x)*gh, e3.y + (o3.y - e3.y)*gh);
        pa[7] = pack2bf(e3.z + (o3.z - e3.z)*gh, e3.w + (o3.w - e3.w)*gh);
        pw[0] = pack2bf(w0.x, w0.y); pw[1] = pack2bf(w0.z, w0.w);
        pw[2] = pack2bf(w1.x, w1.y); pw[3] = pack2bf(w1.z, w1.w);
        pw[4] = pack2bf(w2.x, w2.y); pw[5] = pack2bf(w2.z, w2.w);
        pw[6] = pack2bf(w3.x, w3.y); pw[7] = pack2bf(w3.z, w3.w);
        __syncthreads();

        if (k0 + 64 < EMBD) {
            const float* go = gob + k0 + 64;
            const float* ge = geb + k0 + 64;
            const float* gw = gwb + k0 + 64;
            o0 = *(const float4*)(go);      o1 = *(const float4*)(go + 4);
            o2 = *(const float4*)(go + 8);  o3 = *(const float4*)(go + 12);
            e0 = *(const float4*)(ge);      e1 = *(const float4*)(ge + 4);
            e2 = *(const float4*)(ge + 8);  e3 = *(const float4*)(ge + 12);
            w0 = *(const float4*)(gw);      w1 = *(const float4*)(gw + 4);
            w2 = *(const float4*)(gw + 8);  w3 = *(const float4*)(gw + 12);
        }

        #pragma unroll
        for (int ks = 0; ks < 64; ks += 32) {
            bf16x8 af = *(const bf16x8*)(a_l + (wv*16 + l16) * GPAD + ks + quad*8);
            #pragma unroll
            for (int nt = 0; nt < 4; nt++) {
                bf16x8 wf = *(const bf16x8*)(w_l + (nt*16 + l16) * GPAD + ks + quad*8);
                acc[nt] = __builtin_amdgcn_mfma_f32_16x16x32_bf16(af, wf, acc[nt], 0, 0, 0);
            }
        }
        __syncthreads();
    }

    #pragma unroll
    for (int nt = 0; nt < 4; nt++) {
        const int col = n0 + nt*16 + l16;
        const float bvv = bias[col];
        #pragma unroll
        for (int r = 0; r < 4; r++) {
            const int row = m0 + wv*16 + quad*4 + r;
            out[(size_t)row * EMBD + col] = acc[nt][r] + bvv;
        }
    }
}

// ---------------------------------------------------------------------------
// Fused attn_local + kNN ext-attention. grid 4608 x 256 threads.
// blocks [0,512): local XL causal attention (compute-bound, K/V L3-resident)
// blocks [512,4608): kNN ext attention (streams 536 MB, BW-bound) -> ext_ws
// The two populations co-reside on CUs (36 KB LDS -> 4 blocks/CU), overlapping
// the MFMA/VALU pipe with the HBM stream. Gate-merge happens later in gemm_out.
// ---------------------------------------------------------------------------
#define APAD 72

__global__ __launch_bounds__(256) void attn_knn(
    const float* __restrict__ q_ws,     // [B,S,HD]
    const float* __restrict__ xlm,      // [B,XL,2,HD]
    const float* __restrict__ kv_cur,   // [B,S,2,HD]
    const float* __restrict__ rel,      // [H,S,J]
    const float* __restrict__ knn,      // [B,S,KK,2,HD]
    float* __restrict__ o_ws,           // [B,S,HD] local-attn out
    float* __restrict__ ext_ws)         // [B,S,HD] knn-attn out
{
    __shared__ __align__(16) uint8_t smem[36864];
    const int bid  = blockIdx.x;
    const int t    = threadIdx.x;
    const int wv   = t >> 6;
    const int lane = t & 63;

    if (bid >= 512) {
        // ---------------- kNN ext-attention path ----------------
        float* p_s = (float*)smem;            // [8][32] scores
        const size_t bs = bid - 512;
        const float* base = knn + bs * (size_t)(KK_ * 2 * HD_);
        const int h0 = wv;
        const int h1 = wv + 4;
        const float qv0 = q_ws[bs * HD_ + h0*64 + lane];
        const float qv1 = q_ws[bs * HD_ + h1*64 + lane];

        #pragma unroll 4
        for (int kk = 0; kk < KK_; kk++) {
            const float* krow = base + (size_t)(kk*2) * HD_;
            float pr0 = qv0 * krow[h0*64 + lane];
            float pr1 = qv1 * krow[h1*64 + lane];
            #pragma unroll
            for (int off = 32; off >= 1; off >>= 1) {
                pr0 += __shfl_xor(pr0, off);
                pr1 += __shfl_xor(pr1, off);
            }
            if (lane == 0) { p_s[h0*KK_ + kk] = pr0; p_s[h1*KK_ + kk] = pr1; }
        }
        __syncthreads();

        // softmax: half-wave per head (lanes 0-31 -> h0, 32-63 -> h1)
        const int hh = wv + 4 * (lane >> 5);
        const int kidx = lane & 31;
        const float sval = p_s[hh*KK_ + kidx] * 0.125f;
        float mx = sval;
        #pragma unroll
        for (int off = 16; off >= 1; off >>= 1)
            mx = fmaxf(mx, __shfl_xor(mx, off));
        const float e = __expf(sval - mx);
        float es = e;
        #pragma unroll
        for (int off = 16; off >= 1; off >>= 1)
            es += __shfl_xor(es, off);
        p_s[hh*KK_ + kidx] = e / es;
        __syncthreads();

        float acc0 = 0.f, acc1 = 0.f;
        #pragma unroll 4
        for (int kk = 0; kk < KK_; kk++) {
            const float* vrow = base + (size_t)(kk*2 + 1) * HD_;
            acc0 += p_s[h0*KK_ + kk] * vrow[h0*64 + lane];
            acc1 += p_s[h1*KK_ + kk] * vrow[h1*64 + lane];
        }
        ext_ws[bs * HD_ + h0*64 + lane] = acc0;
        ext_ws[bs * HD_ + h1*64 + lane] = acc1;
        return;
    }

    // ---------------- local XL causal attention path ----------------
    uint16_t (*qS)[APAD]     = (uint16_t(*)[APAD])(smem);            // 9216 B
    uint16_t (*kS)[APAD]     = (uint16_t(*)[APAD])(smem + 9216);
    uint16_t (*vS)[APAD]     = (uint16_t(*)[APAD])(smem + 18432);
    uint16_t (*pS)[16][APAD] = (uint16_t(*)[16][APAD])(smem + 27648);

    const int quad = lane >> 4;
    const int l16  = lane & 15;
    const int b    = bid >> 7;
    const int h    = (bid >> 4) & 7;
    const int i0   = (bid & 15) * 64;

    const int irow0  = i0 + wv*16 + quad*4;
    const int ntiles = ((i0 + XL_ + 63) >> 6) + 1;
    const float scale = 0.125f;

    const int kj  = t >> 2;          // K staging: j row 0..63
    const int kdc = (t & 3) * 16;    //            d chunk (16)
    const int vj  = (t & 31) * 2;    // V staging: j pair
    const int vdc = (t >> 5) * 8;    //            d chunk (8)

    {   // stage Q once
        const int row = t >> 2;
        const int dc  = (t & 3) * 16;
        const float* g = q_ws + (size_t)(b*S_ + i0 + row) * HD_ + h*D_ + dc;
        float4 x0 = *(const float4*)(g);
        float4 x1 = *(const float4*)(g + 4);
        float4 x2 = *(const float4*)(g + 8);
        float4 x3 = *(const float4*)(g + 12);
        uint32_t* d = (uint32_t*)&qS[row][dc];
        d[0] = pack2bf(x0.x, x0.y); d[1] = pack2bf(x0.z, x0.w);
        d[2] = pack2bf(x1.x, x1.y); d[3] = pack2bf(x1.z, x1.w);
        d[4] = pack2bf(x2.x, x2.y); d[5] = pack2bf(x2.z, x2.w);
        d[6] = pack2bf(x3.x, x3.y); d[7] = pack2bf(x3.z, x3.w);
    }

    // preload K/V tile 0 into registers
    float4 kx0, kx1, kx2, kx3, va0, va1, vb0, vb1;
    {
        const int jg = kj;
        const float* g = (jg < XL_)
            ? xlm + ((size_t)(b*XL_ + jg) * 2) * HD_ + h*D_ + kdc
            : kv_cur + ((size_t)(b*S_ + (jg - XL_)) * 2) * HD_ + h*D_ + kdc;
        kx0 = *(const float4*)(g);
        kx1 = *(const float4*)(g + 4);
        kx2 = *(const float4*)(g + 8);
        kx3 = *(const float4*)(g + 12);
        const int jgv = vj;
        const float* g0 = (jgv < XL_)
            ? xlm + ((size_t)(b*XL_ + jgv) * 2 + 1) * HD_ + h*D_ + vdc
            : kv_cur + ((size_t)(b*S_ + (jgv - XL_)) * 2 + 1) * HD_ + h*D_ + vdc;
        va0 = *(const float4*)(g0);
        va1 = *(const float4*)(g0 + 4);
        vb0 = *(const float4*)(g0 + 2*HD_);
        vb1 = *(const float4*)(g0 + 2*HD_ + 4);
    }

    __syncthreads();    // Q visible to all waves
    const bf16x8 aq0 = *(const bf16x8*)&qS[wv*16 + l16][quad*8];
    const bf16x8 aq1 = *(const bf16x8*)&qS[wv*16 + l16][32 + quad*8];

    f32x4 zero = {0.f, 0.f, 0.f, 0.f};
    f32x4 accO[4] = {zero, zero, zero, zero};
    float m_r[4], l_r[4];
    #pragma unroll
    for (int r = 0; r < 4; r++) { m_r[r] = -1e30f; l_r[r] = 0.f; }

    const float* relbase = rel + ((size_t)h*S_ + irow0) * J_ + l16;

    for (int tix = 0; tix < ntiles; tix++) {
        const int j0 = tix << 6;
        {   // pack prefetched K tile -> LDS (row-major bf16)
            uint32_t* d = (uint32_t*)&kS[kj][kdc];
            d[0] = pack2bf(kx0.x, kx0.y); d[1] = pack2bf(kx0.z, kx0.w);
            d[2] = pack2bf(kx1.x, kx1.y); d[3] = pack2bf(kx1.z, kx1.w);
            d[4] = pack2bf(kx2.x, kx2.y); d[5] = pack2bf(kx2.z, kx2.w);
            d[6] = pack2bf(kx3.x, kx3.y); d[7] = pack2bf(kx3.z, kx3.w);
        }
        {   // pack prefetched V tile -> LDS transposed: vS[d][j]
            *(uint32_t*)&vS[vdc+0][vj] = pack2bf(va0.x, vb0.x);
            *(uint32_t*)&vS[vdc+1][vj] = pack2bf(va0.y, vb0.y);
            *(uint32_t*)&vS[vdc+2][vj] = pack2bf(va0.z, vb0.z);
            *(uint32_t*)&vS[vdc+3][vj] = pack2bf(va0.w, vb0.w);
            *(uint32_t*)&vS[vdc+4][vj] = pack2bf(va1.x, vb1.x);
            *(uint32_t*)&vS[vdc+5][vj] = pack2bf(va1.y, vb1.y);
            *(uint32_t*)&vS[vdc+6][vj] = pack2bf(va1.z, vb1.z);
            *(uint32_t*)&vS[vdc+7][vj] = pack2bf(va1.w, vb1.w);
        }
        __syncthreads();

        if (tix + 1 < ntiles) {   // prefetch next K/V tile; retires under MFMA/softmax
            const int jg = j0 + 64 + kj;
            const float* g = (jg < XL_)
                ? xlm + ((size_t)(b*XL_ + jg) * 2) * HD_ + h*D_ + kdc
                : kv_cur + ((size_t)(b*S_ + (jg - XL_)) * 2) * HD_ + h*D_ + kdc;
            kx0 = *(const float4*)(g);
            kx1 = *(const float4*)(g + 4);
            kx2 = *(const float4*)(g + 8);
            kx3 = *(const float4*)(g + 12);
            const int jgv = j0 + 64 + vj;
            const float* g0 = (jgv < XL_)
                ? xlm + ((size_t)(b*XL_ + jgv) * 2 + 1) * HD_ + h*D_ + vdc
                : kv_cur + ((size_t)(b*S_ + (jgv - XL_)) * 2 + 1) * HD_ + h*D_ + vdc;
            va0 = *(const float4*)(g0);
            va1 = *(const float4*)(g0 + 4);
            vb0 = *(const float4*)(g0 + 2*HD_);
            vb1 = *(const float4*)(g0 + 2*HD_ + 4);
        }

        // rel_pos for this lane's 16 S entries
        float srel[4][4];
        const float* rb = relbase + j0;
        #pragma unroll
        for (int r = 0; r < 4; r++)
            #pragma unroll
            for (int jt = 0; jt < 4; jt++)
                srel[r][jt] = rb[(size_t)r * J_ + jt*16];

        // QK^T: D[row=quad*4+r][col=jt*16+l16]
        f32x4 sac[4] = {zero, zero, zero, zero};
        #pragma unroll
        for (int jt = 0; jt < 4; jt++) {
            bf16x8 bk0 = *(const bf16x8*)&kS[jt*16 + l16][quad*8];
            bf16x8 bk1 = *(const bf16x8*)&kS[jt*16 + l16][32 + quad*8];
            sac[jt] = __builtin_amdgcn_mfma_f32_16x16x32_bf16(aq0, bk0, sac[jt], 0, 0, 0);
            sac[jt] = __builtin_amdgcn_mfma_f32_16x16x32_bf16(aq1, bk1, sac[jt], 0, 0, 0);
        }

        const bool need_mask = (j0 + 64 > i0 + XL_);

        float p_[4][4];
        float alpha[4];
        #pragma unroll
        for (int r = 0; r < 4; r++) {
            const int irow = irow0 + r;
            float sv[4];
            #pragma unroll
            for (int jt = 0; jt < 4; jt++) {
                float s = (sac[jt][r] + srel[r][jt]) * scale;
                if (need_mask && (j0 + jt*16 + l16 > irow + XL_)) s = -1e30f;
                sv[jt] = s;
            }
            float mx = fmaxf(fmaxf(sv[0], sv[1]), fmaxf(sv[2], sv[3]));
            #pragma unroll
            for (int off = 8; off >= 1; off >>= 1)
                mx = fmaxf(mx, __shfl_xor(mx, off));
            const float mnew = fmaxf(m_r[r], mx);
            alpha[r] = __expf(m_r[r] - mnew);
            m_r[r] = mnew;
            float ps = 0.f;
            #pragma unroll
            for (int jt = 0; jt < 4; jt++) {
                p_[jt][r] = __expf(sv[jt] - mnew);
                ps += p_[jt][r];
            }
            #pragma unroll
            for (int off = 8; off >= 1; off >>= 1)
                ps += __shfl_xor(ps, off);
            l_r[r] = l_r[r] * alpha[r] + ps;
        }
        #pragma unroll
        for (int dt = 0; dt < 4; dt++)
            #pragma unroll
            for (int r = 0; r < 4; r++)
                accO[dt][r] *= alpha[r];

        // P -> per-wave LDS as bf16 (same-wave RAW)
        #pragma unroll
        for (int jt = 0; jt < 4; jt++)
            #pragma unroll
            for (int r = 0; r < 4; r++)
                pS[wv][quad*4 + r][jt*16 + l16] = (uint16_t)pack2bf(p_[jt][r], 0.f);

        // PV: A=P (m=i_local, k=j), B=V^T (n=d, k=j)
        #pragma unroll
        for (int kc = 0; kc < 2; kc++) {
            bf16x8 ap = *(const bf16x8*)&pS[wv][l16][kc*32 + quad*8];
            #pragma unroll
            for (int dt = 0; dt < 4; dt++) {
                bf16x8 bv = *(const bf16x8*)&vS[dt*16 + l16][kc*32 + quad*8];
                accO[dt] = __builtin_amdgcn_mfma_f32_16x16x32_bf16(ap, bv, accO[dt], 0, 0, 0);
            }
        }
        __syncthreads();
    }

    #pragma unroll
    for (int r = 0; r < 4; r++) {
        const float inv = 1.f / l_r[r];
        float* o = o_ws + (size_t)(b*S_ + irow0 + r) * HD_ + h*D_ + l16;
        #pragma unroll
        for (int dt = 0; dt < 4; dt++)
            o[dt*16] = accO[dt][r] * inv;
    }
}

// ---------------------------------------------------------------------------
extern "C" void kernel_launch(void* const* d_in, const int* in_sizes, int n_in,
                              void* d_out, int out_size, void* d_ws, size_t ws_size,
                              hipStream_t stream)
{
    (void)in_sizes; (void)n_in; (void)out_size; (void)ws_size;
    const float* x    = (const float*)d_in[0];
    const float* rel  = (const float*)d_in[1];
    const float* xlm  = (const float*)d_in[2];
    const float* knn  = (const float*)d_in[3];
    const float* Wq   = (const float*)d_in[4];
    const float* bq   = (const float*)d_in[5];
    const float* Wk   = (const float*)d_in[6];
    const float* bk   = (const float*)d_in[7];
    const float* Wv   = (const float*)d_in[8];
    const float* bv   = (const float*)d_in[9];
    const float* Wo   = (const float*)d_in[10];
    const float* bo   = (const float*)d_in[11];
    const float* gate = (const float*)d_in[12];

    float* out    = (float*)d_out;
    float* kv_out = out + OUT1;           // [B,S,2,HD] second output
    float* q_ws   = (float*)d_ws;         // [B,S,HD]
    float* o_ws   = q_ws + OUT1;          // [B,S,HD] local-attn out
    float* ext_ws = o_ws + OUT1;          // [B,S,HD] knn-attn out

    gemm_qkv<<<dim3(64, 8, 3), 256, 0, stream>>>(x, Wq, bq, Wk, bk, Wv, bv, q_ws, kv_out);
    attn_knn<<<dim3(4608), 256, 0, stream>>>(q_ws, xlm, kv_out, rel, knn, o_ws, ext_ws);
    gemm_out<<<dim3(64, 8), 256, 0, stream>>>(o_ws, ext_ws, gate, Wo, bo, out);
}